// Round 11
// baseline (27848.941 us; speedup 1.0000x reference)
//
#include <hip/hip_runtime.h>
#include <math.h>

#define T 600
#define NBLK 235

// ---------- sync layout (uints in ws[0..8192)) ----------
#define FL1 256
#define FL2 768
#define FL3 1280
#define FLB 1792
#define SH1 2304
#define SH2 2880
#define SH3 3520

// ---------- ws float offsets ----------
#define OFF_UT1 8192
#define SZ_UT1 (1600*480)
#define OFF_UT2 (OFF_UT1 + SZ_UT1)
#define SZ_UT2 (1600*960)
#define OFF_UT3 (OFF_UT2 + SZ_UT2)
#define OFF_WWT (OFF_UT3 + SZ_UT2)
#define SZ_WWT (30*400)
#define OFF_H1 (OFF_WWT + SZ_WWT)
#define SZ_H (600*32*400)
#define OFF_H2 (OFF_H1 + SZ_H)
#define OFF_H3 (OFF_H2 + SZ_H)
#define OFF_W  (OFF_H3 + SZ_H)
#define SZ_W (600*32*61)
#define OFF_SP (OFF_W + SZ_W)          // padded sentence [32][64][64]
#define SZ_SP (32*64*64)

// ---------- dynamic LDS float offsets ----------
#define LDS_W    0
#define LDS_V    19280
#define LDS_Z    34640
#define LDS_C    35408
#define LDS_TOT  35600        // 142400 bytes
// role-0 local-attention scratch (tail of W region; role0 w4 ends at 11616)
#define A0_KAP 11616   // 320
#define A0_P   11936   // 960
#define A0_AB  12896   // 640
#define A0_PHI 13536   // 2048
#define A0_WB  15584   // 1952 -> ends 17536 < 19280

__device__ __forceinline__ float sigm(float x) { return 1.f/(1.f+expf(-x)); }

__global__ void init_ws(unsigned* uws) {
    for (int i = threadIdx.x + blockIdx.x*blockDim.x; i < 8192; i += blockDim.x*gridDim.x)
        uws[i] = 0u;
}

__global__ void build_ut(float* __restrict__ ws,
                         const float* __restrict__ W1, const float* __restrict__ U1r,
                         const float* __restrict__ W2, const float* __restrict__ U2r,
                         const float* __restrict__ W3, const float* __restrict__ U3r,
                         const float* __restrict__ Ww, const float* __restrict__ sentence) {
    const long N1 = 1600L*480, N2 = 1600L*960;
    const long total = N1 + 2*N2 + 30L*400 + SZ_SP;
    for (long i = blockIdx.x*(long)blockDim.x + threadIdx.x; i < total;
         i += (long)gridDim.x*blockDim.x) {
        if (i < N1) {
            long c = i / 480, k = i % 480;
            float v = 0.f;
            if (k < 64) v = W1[k*1600 + c];
            else if (k < 464) v = U1r[(k-64)*1600 + c];
            ws[OFF_UT1 + c*480 + k] = v;
        } else if (i < N1 + N2) {
            long ii = i - N1; long c = ii/960, k = ii%960;
            float v = 0.f;
            if (k < 464) v = W2[k*1600 + c];
            else if (k >= 480 && k < 880) v = U2r[(k-480)*1600 + c];
            ws[OFF_UT2 + c*960 + k] = v;
        } else if (i < N1 + 2*N2) {
            long ii = i - N1 - N2; long c = ii/960, k = ii%960;
            float v = 0.f;
            if (k < 464) v = W3[k*1600 + c];
            else if (k >= 480 && k < 880) v = U3r[(k-480)*1600 + c];
            ws[OFF_UT3 + c*960 + k] = v;
        } else if (i < N1 + 2*N2 + 12000) {
            long ii = i - N1 - 2*N2; long n = ii/400, k = ii%400;
            ws[OFF_WWT + n*400 + k] = Ww[k*30 + n];
        } else {
            long ii = i - N1 - 2*N2 - 12000;     // 0..131071
            long b = ii >> 12, r = ii & 4095, u = r >> 6, v = r & 63;
            ws[OFF_SP + ii] = (v < 61) ? sentence[b*3904 + u*61 + v] : 0.f;
        }
    }
}

// ---------- sync primitives (clean-line protocol, R10-verified) ----------
__device__ __forceinline__ unsigned ld_cohere(const unsigned* p) {
    unsigned v;
    asm volatile("global_load_dword %0, %1, off sc0 sc1\n\t"
                 "s_waitcnt vmcnt(0)"
                 : "=v"(v) : "v"(p) : "memory");
    return v;
}
__device__ __forceinline__ void st_wt(float* p, float v) {
    asm volatile("global_store_dword %0, %1, off sc0 sc1\n\t"
                 "s_waitcnt vmcnt(0)"
                 :: "v"(p), "v"(v) : "memory");
}
__device__ __forceinline__ void publish(unsigned* flags, unsigned v) {
    #pragma unroll
    for (int r = 0; r < 8; ++r)
        asm volatile("global_store_dword %0, %1, off sc0 sc1"
                     :: "v"(flags + r*64), "v"(v) : "memory");
    asm volatile("s_waitcnt vmcnt(0)" ::: "memory");
}
__device__ __forceinline__ void wait_flag(const unsigned* p, unsigned tgt) {
    int it = 0;
    while (ld_cohere(p) < tgt) {
        if (it > 32) __builtin_amdgcn_s_sleep(2);
        ++it;
    }
}
__device__ __forceinline__ void arrive2(unsigned* shard, unsigned gsize,
                                        unsigned* master, unsigned n,
                                        unsigned* flags, unsigned ep1) {
    unsigned old = __hip_atomic_fetch_add(shard, 1u, __ATOMIC_RELAXED,
                                          __HIP_MEMORY_SCOPE_AGENT);
    if (old + 1u == gsize * ep1) {
        unsigned o2 = __hip_atomic_fetch_add(master, gsize, __ATOMIC_RELAXED,
                                             __HIP_MEMORY_SCOPE_AGENT);
        if (o2 + gsize == n * ep1) publish(flags, ep1);
    }
}
__device__ __forceinline__ void arrive1(unsigned* master, unsigned n,
                                        unsigned* flags, unsigned ep1) {
    unsigned old = __hip_atomic_fetch_add(master, 1u, __ATOMIC_RELAXED,
                                          __HIP_MEMORY_SCOPE_AGENT);
    if (old + 1u == n * ep1) publish(flags, ep1);
}

// ---------- GEMM inner pass over kf range [LO,HI) ----------
template<int NQ, int KCN, int K4S, int LO, int HI>
__device__ __forceinline__ void gemm_pass(const float4* __restrict__ w4,
                                          const float4* __restrict__ v4,
                                          int lc0, int kc, int bq, int kofs4,
                                          float acc[8][4]) {
    #pragma unroll
    for (int q = 0; q < NQ; ++q) {
        int kfv = q*KCN + kc;
        if (kfv >= LO && kfv < HI) {
            int xv = kfv ^ ((kfv >> 3) & 7);
            int kfw = kofs4 + kfv;
            int xw = kfw ^ ((kfw >> 3) & 7);
            float4 va[8];
            #pragma unroll
            for (int i = 0; i < 8; ++i) va[i] = v4[(bq*8+i)*120 + xv];
            #pragma unroll
            for (int j = 0; j < 4; ++j) {
                float4 u = w4[(lc0+j)*K4S + xw];
                #pragma unroll
                for (int i = 0; i < 8; ++i)
                    acc[i][j] += va[i].x*u.x + va[i].y*u.y + va[i].z*u.z + va[i].w*u.w;
            }
        }
    }
}

__launch_bounds__(512)
__global__ void hw_main(float* __restrict__ ws,
                        const float* __restrict__ strokes, const float* __restrict__ sentence,
                        const float* __restrict__ b1, const float* __restrict__ b2,
                        const float* __restrict__ b3, const float* __restrict__ bw) {
    extern __shared__ float S[];
    const int tid = threadIdx.x;
    const int bid = blockIdx.x;
    unsigned* uws = (unsigned*)ws;
    unsigned* root1 = uws + 0;
    unsigned* root2 = uws + 64;
    unsigned* root3 = uws + 128;
    unsigned* rootB = uws + 192;
    const int rep = (bid & 7) * 64;
    const unsigned* fl1r = uws + FL1 + rep;
    const unsigned* fl2r = uws + FL2 + rep;
    const unsigned* flBr = uws + FLB + rep;

    // roles: [0,67) L1 ; [67,147) L2 ; [147,227) L3 ; [227,235) ATT
    int role, unit0 = 0, nu = 0, L = 0, b0a = 0;
    const float* utp = nullptr; const float* biasp = nullptr; float* hout = nullptr;
    if (bid < 67)       { role = 0; L = bid;      unit0 = L*6; nu = (bid==66)?4:6; utp = ws+OFF_UT1; biasp = b1; hout = ws+OFF_H1; }
    else if (bid < 147) { role = 1; L = bid-67;   unit0 = L*5; nu = 5;             utp = ws+OFF_UT2; biasp = b2; hout = ws+OFF_H2; }
    else if (bid < 227) { role = 2; L = bid-147;  unit0 = L*5; nu = 5;             utp = ws+OFF_UT3; biasp = b3; hout = ws+OFF_H3; }
    else                { role = 3; b0a = (bid-227)*4; }

    if (role <= 2) {
        const int NC = 4*nu;
        const int KCN = (role == 0) ? 20 : 24;
        const int K4S = (role == 0) ? 121 : 241;
        const int K4TOT = (role == 0) ? 120 : 240;
        const int uts = (role == 0) ? 480 : 960;
        float4* w4 = (float4*)S;
        float4* v4 = (float4*)(S + LDS_V);
        float*  vf = S + LDS_V;
        float*  z_lds = S + LDS_Z;
        float*  c_lds = S + LDS_C;
        // role-0 local attention scratch
        float* kapL  = S + A0_KAP;
        float* pbufL = S + A0_P;
        float* abL   = S + A0_AB;
        float* phiL  = S + A0_PHI;
        float* wbufL = S + A0_WB;

        for (int idx = tid; idx < NC*K4TOT; idx += 512) {
            int colL = idx / K4TOT, kf = idx % K4TOT;
            int gcol = (colL/nu)*400 + unit0 + (colL%nu);
            float4 val = *(const float4*)(utp + (size_t)gcol*uts + kf*4);
            w4[colL*K4S + (kf ^ ((kf>>3)&7))] = val;
        }
        for (int i = tid; i < 192; i += 512) c_lds[i] = 0.f;
        if (role == 0) {
            for (int i = tid; i < 320; i += 512) kapL[i] = 0.f;
            for (int i = tid; i < 1952; i += 512) wbufL[i] = 0.f;
        }

        const int tile = tid / KCN, kc = tid % KCN;
        const int bq = tile / nu, cq = tile % nu;
        const bool act = (tile < 4*nu);
        float bias0 = 0.f, bias1 = 0.f;
        if (tid < 32*NC)       { int lc = tid % NC;        bias0 = biasp[(lc/nu)*400 + unit0 + (lc%nu)]; }
        if (tid + 512 < 32*NC) { int lc = (tid+512) % NC;  bias1 = biasp[(lc/nu)*400 + unit0 + (lc%nu)]; }
        const unsigned nrole = (role == 0) ? 67u : 80u;
        unsigned* mymaster = (role == 0) ? root1 : ((role == 1) ? root2 : root3);
        unsigned* myfl     = uws + ((role == 0) ? FL1 : ((role == 1) ? FL2 : FL3));
        const unsigned* myflr = uws + ((role == 0) ? FL1 : ((role == 1) ? FL2 : FL3)) + rep;
        unsigned* myshard;
        {
            int shbase = (role == 0) ? SH1 : ((role == 1) ? SH2 : SH3);
            myshard = uws + shbase + (L >> 3) * 64;
        }
        const unsigned gsize = (unsigned)(((int)nrole - (L >> 3)*8 < 8) ? ((int)nrole - (L >> 3)*8) : 8);
        __syncthreads();

        for (int t = 0; t < T; ++t) {
            float acc[8][4];
            #pragma unroll
            for (int i = 0; i < 8; ++i)
                #pragma unroll
                for (int j = 0; j < 4; ++j) acc[i][j] = 0.f;

            if (role == 0) {
                // ======== L1(t): ONE handoff (fl1). Local attention in prologue. ========
                if (tid == 0 && t > 0) wait_flag(myflr, (unsigned)t);
                __syncthreads();
                const float* hsrc = (t > 0) ? (ws + OFF_H1 + (size_t)(t-1)*12800) : nullptr;
                for (int idx = tid; idx < 32*104; idx += 512) {
                    int b = idx/104, kf = 16 + idx%104;
                    float4 val = {0.f,0.f,0.f,0.f};
                    if (kf < 116 && hsrc) val = *(const float4*)(hsrc + b*400 + (kf*4 - 64));
                    v4[b*120 + (kf ^ ((kf>>3)&7))] = val;
                }
                __syncthreads();
                if (t > 0) {
                    // ---- p = h1(t-1) @ WwT + bw  (coalesced float4 over k) ----
                    if (tid < 480) {
                        int n = tid % 30, g = tid / 30;      // g 0..15 -> batches 2g,2g+1
                        int bA = g*2, bB = bA + 1;
                        const float4* wt4 = (const float4*)(ws + OFF_WWT) + n*100;
                        float a0 = 0.f, a1 = 0.f;
                        #pragma unroll 4
                        for (int kfi = 0; kfi < 100; ++kfi) {
                            int kf = kfi + 16;
                            int xv = kf ^ ((kf>>3)&7);
                            float4 wv = wt4[kfi];
                            float4 hA = v4[bA*120 + xv];
                            float4 hB = v4[bB*120 + xv];
                            a0 += hA.x*wv.x + hA.y*wv.y + hA.z*wv.z + hA.w*wv.w;
                            a1 += hB.x*wv.x + hB.y*wv.y + hB.z*wv.z + hB.w*wv.w;
                        }
                        float bwn = bw[n];
                        pbufL[bA*30 + n] = a0 + bwn;
                        pbufL[bB*30 + n] = a1 + bwn;
                    }
                    __syncthreads();
                    if (tid < 320) {
                        int b = tid/10, k0 = tid%10;
                        float al = expf(pbufL[b*30 + k0]);
                        float be = expf(pbufL[b*30 + 10 + k0]);
                        kapL[b*10 + k0] += expf(pbufL[b*30 + 20 + k0]);
                        abL[b*20 + k0] = al;
                        abL[b*20 + 10 + k0] = be;
                    }
                    __syncthreads();
                    for (int o = tid; o < 2048; o += 512) {
                        int b = o >> 6, u = o & 63;
                        float uf = (float)u, ph = 0.f;
                        #pragma unroll
                        for (int k0 = 0; k0 < 10; ++k0) {
                            float d = kapL[b*10 + k0] - uf;
                            ph += abL[b*20 + k0]*expf(-abL[b*20 + 10 + k0]*d*d);
                        }
                        phiL[o] = ph;
                    }
                    __syncthreads();
                    // ---- w = phi . sentp  (aligned float4, register accum over u) ----
                    {
                        int b = tid >> 4, v4i = tid & 15;
                        const float4* sp4 = (const float4*)(ws + OFF_SP) + ((size_t)b*64)*16 + v4i;
                        const float* phb = phiL + b*64;
                        float4 a4 = {0.f,0.f,0.f,0.f};
                        #pragma unroll 4
                        for (int u = 0; u < 64; ++u) {
                            float pv = phb[u];
                            float4 s4 = sp4[(size_t)u*16];
                            a4.x += pv*s4.x; a4.y += pv*s4.y;
                            a4.z += pv*s4.z; a4.w += pv*s4.w;
                        }
                        int v0 = v4i*4;
                        wbufL[b*61 + v0] = a4.x;
                        if (v0 + 3 < 61) {
                            wbufL[b*61 + v0+1] = a4.y;
                            wbufL[b*61 + v0+2] = a4.z;
                            wbufL[b*61 + v0+3] = a4.w;
                        }
                    }
                    __syncthreads();
                }
                // head fill: [x(t), w(t-1)] from strokes + wbufL
                {
                    int b = tid >> 4, kf = tid & 15;
                    if (b < 32) {
                        float4 val;
                        if (kf == 0) {
                            const float* xp = strokes + ((size_t)b*600 + t)*3;
                            val.x = xp[0]; val.y = xp[1]; val.z = xp[2];
                            val.w = wbufL[b*61];
                        } else {
                            int k0 = kf*4 - 3;
                            val.x = wbufL[b*61+k0];   val.y = wbufL[b*61+k0+1];
                            val.z = wbufL[b*61+k0+2]; val.w = wbufL[b*61+k0+3];
                        }
                        v4[b*120 + (kf ^ ((kf>>3)&7))] = val;
                    }
                }
                __syncthreads();
                if (act) gemm_pass<6,20,121,0,116>(w4, v4, cq*4, kc, bq, 0, acc);
            } else {
                // ---- L2/L3(t): h-part after up-flag; w-part after flB; pass2 after own flag ----
                if (tid == 0) wait_flag((role==1) ? fl1r : fl2r, (unsigned)(t+1));
                __syncthreads();
                const float* hsrc = ws + ((role==1)?OFF_H1:OFF_H2) + (size_t)t*12800;
                for (int idx = tid; idx < 32*104; idx += 512) {
                    int b = idx/104, kf = 16 + idx%104;
                    float4 val = {0.f,0.f,0.f,0.f};
                    if (kf < 116) val = *(const float4*)(hsrc + b*400 + (kf*4 - 64));
                    v4[b*120 + (kf ^ ((kf>>3)&7))] = val;
                }
                __syncthreads();
                if (act) gemm_pass<5,24,241,16,116>(w4, v4, cq*4, kc, bq, 0, acc);
                if (tid == 0) wait_flag(flBr, (unsigned)(t+1));
                __syncthreads();
                const float* wsrc = ws + OFF_W + (size_t)t*1952;
                {
                    int b = tid / 16, kf = tid % 16;
                    if (b < 32) {
                        float4 val;
                        if (kf == 0) {
                            const float* xp = strokes + ((size_t)b*600 + t)*3;
                            val.x = xp[0]; val.y = xp[1]; val.z = xp[2];
                            val.w = wsrc[b*61];
                        } else {
                            int k0 = kf*4 - 3;
                            val.x = wsrc[b*61+k0]; val.y = wsrc[b*61+k0+1];
                            val.z = wsrc[b*61+k0+2]; val.w = wsrc[b*61+k0+3];
                        }
                        v4[b*120 + (kf ^ ((kf>>3)&7))] = val;
                    }
                }
                __syncthreads();
                if (act) gemm_pass<5,24,241,0,16>(w4, v4, cq*4, kc, bq, 0, acc);
                __syncthreads();
                if (tid == 0 && t > 0) wait_flag(myflr, (unsigned)t);
                __syncthreads();
                const float* hp2 = (t > 0) ? (ws + ((role==1)?OFF_H2:OFF_H3) + (size_t)(t-1)*12800) : nullptr;
                for (int idx = tid; idx < 32*120; idx += 512) {
                    int b = idx/120, kf = idx%120;
                    float4 val = {0.f,0.f,0.f,0.f};
                    if (kf < 100 && hp2) val = *(const float4*)(hp2 + b*400 + kf*4);
                    v4[b*120 + (kf ^ ((kf>>3)&7))] = val;
                }
                __syncthreads();
                if (act) gemm_pass<5,24,241,0,100>(w4, v4, cq*4, kc, bq, 120, acc);
            }

            // ---- split-K reduction (scratch aliases v) ----
            __syncthreads();
            const int halfk = (KCN+1)/2;
            const int SCRW = NC*32 + 4;
            const int NO = 32*NC;
            if (act && kc < halfk) {
                #pragma unroll
                for (int i = 0; i < 8; ++i) {
                    float4 w;
                    w.x=acc[i][0]; w.y=acc[i][1]; w.z=acc[i][2]; w.w=acc[i][3];
                    *(float4*)&vf[kc*SCRW + (bq*8+i)*NC + cq*4] = w;
                }
            }
            __syncthreads();
            float zs0 = 0.f, zs1 = 0.f;
            if (tid < NO)       for (int k2 = 0; k2 < halfk; ++k2) zs0 += vf[k2*SCRW + tid];
            if (tid + 512 < NO) for (int k2 = 0; k2 < halfk; ++k2) zs1 += vf[k2*SCRW + tid + 512];
            __syncthreads();
            if (act && kc >= halfk) {
                #pragma unroll
                for (int i = 0; i < 8; ++i) {
                    float4 w;
                    w.x=acc[i][0]; w.y=acc[i][1]; w.z=acc[i][2]; w.w=acc[i][3];
                    *(float4*)&vf[(kc-halfk)*SCRW + (bq*8+i)*NC + cq*4] = w;
                }
            }
            __syncthreads();
            const int rem = KCN - halfk;
            if (tid < NO) {
                for (int k2 = 0; k2 < rem; ++k2) zs0 += vf[k2*SCRW + tid];
                z_lds[tid] = zs0 + bias0;
            }
            if (tid + 512 < NO) {
                for (int k2 = 0; k2 < rem; ++k2) zs1 += vf[k2*SCRW + tid + 512];
                z_lds[tid + 512] = zs1 + bias1;
            }
            __syncthreads();
            if (tid < 32*nu) {
                int b = tid & 31, ju = tid >> 5;
                float zi = z_lds[b*NC + ju];
                float zf = z_lds[b*NC + nu + ju];
                float zg = z_lds[b*NC + 2*nu + ju];
                float zo = z_lds[b*NC + 3*nu + ju];
                float cP = c_lds[b*6 + ju];
                float cN = sigm(zf)*cP + sigm(zi)*tanhf(zg);
                float hN = sigm(zo)*tanhf(cN);
                c_lds[b*6 + ju] = cN;
                st_wt(&hout[(size_t)t*12800 + b*400 + unit0 + ju], hN);
            }
            __syncthreads();
            if (tid == 0) arrive2(myshard, gsize, mymaster, nrole, myfl, (unsigned)(t+1));
        }
    } else {
        // ------------------- ATT block (4 batches): w for L2/L3 only -------------------
        float* hb   = S;
        float* pp   = S + 1600;
        float* pbuf = S + 2080;
        float* ab   = S + 2208;
        float* phiB = S + 2304;
        float* kap  = S + 2560;
        float* bwl  = S + 2600;
        float* sentl= S + 2640;
        float* wwt  = S + 18256;

        for (int i = tid; i < 40; i += 512) kap[i] = 0.f;
        for (int i = tid; i < 30; i += 512) bwl[i] = bw[i];
        for (int i = tid; i < 15616; i += 512) sentl[i] = sentence[(size_t)b0a*3904 + i];
        for (int i = tid; i < 12000; i += 512) {
            int n = i/400, k = i%400;
            wwt[n*401 + k] = ws[OFF_WWT + i];
        }
        __syncthreads();

        for (int t = 0; t < T; ++t) {
            if (tid == 0) wait_flag(fl1r, (unsigned)(t+1));
            __syncthreads();
            const float* h1t = ws + OFF_H1 + (size_t)t*12800 + (size_t)b0a*400;
            if (tid < 400) *(float4*)&hb[tid*4] = *(const float4*)(h1t + tid*4);
            __syncthreads();
            if (tid < 480) {
                int bb = tid/120, r = tid%120, n = r >> 2, kc4 = r & 3;
                const float* wwn = wwt + n*401;
                float sacc = 0.f;
                for (int k = kc4*100; k < kc4*100 + 100; ++k) sacc += hb[bb*400 + k]*wwn[k];
                pp[bb*120 + n*4 + kc4] = sacc;
            }
            __syncthreads();
            if (tid < 120) {
                int bb = tid/30, n = tid%30;
                pbuf[tid] = pp[bb*120+n*4] + pp[bb*120+n*4+1] + pp[bb*120+n*4+2] + pp[bb*120+n*4+3] + bwl[n];
            }
            __syncthreads();
            if (tid < 40) {
                int bb = tid/10, k0 = tid%10;
                float a  = expf(pbuf[bb*30 + k0]);
                float be = expf(pbuf[bb*30 + 10 + k0]);
                float kv = kap[bb*10 + k0] + expf(pbuf[bb*30 + 20 + k0]);
                kap[bb*10 + k0] = kv;
                ab[bb*20 + k0] = a;
                ab[bb*20 + 10 + k0] = be;
            }
            __syncthreads();
            if (tid < 256) {
                int bb = tid/64, u = tid%64;
                float uf = (float)u, ph = 0.f;
                for (int k0 = 0; k0 < 10; ++k0) {
                    float d = kap[bb*10 + k0] - uf;
                    ph += ab[bb*20 + k0]*expf(-ab[bb*20 + 10 + k0]*d*d);
                }
                phiB[tid] = ph;
            }
            __syncthreads();
            if (tid < 244) {
                int bb = tid/61, v = tid%61;
                const float* sp = sentl + bb*3904 + v;
                float wv = 0.f;
                for (int u = 0; u < 64; ++u) wv += phiB[bb*64 + u]*sp[u*61];
                st_wt(&ws[OFF_W + (size_t)t*1952 + (b0a+bb)*61 + v], wv);
            }
            __syncthreads();
            if (tid == 0) arrive1(rootB, 8u, uws + FLB, (unsigned)(t+1));
        }
    }
}

__launch_bounds__(256)
__global__ void out_proj(const float* __restrict__ ws, const float* __restrict__ Wm,
                         const float* __restrict__ bm, float* __restrict__ out) {
    __shared__ __align__(16) float hc[8*1200];
    __shared__ float yy[8*121];
    __shared__ float sm2[16];
    const int tid = threadIdx.x;
    const long rowbase = (long)blockIdx.x * 8;
    const float* h1h = ws + OFF_H1;
    const float* h2h = ws + OFF_H2;
    const float* h3h = ws + OFF_H3;
    for (int idx = tid; idx < 8*1200; idx += 256) {
        int i = idx/1200, k = idx%1200;
        long r = rowbase + i; int t = (int)(r >> 5), b = (int)(r & 31);
        float v;
        if (k < 400)      v = h1h[(size_t)t*12800 + b*400 + k];
        else if (k < 800) v = h2h[(size_t)t*12800 + b*400 + (k-400)];
        else              v = h3h[(size_t)t*12800 + b*400 + (k-800)];
        hc[i*1200 + k] = v;
    }
    __syncthreads();
    const int j = tid & 127, rr = tid >> 7;
    if (j < 121) {
        float a0=0.f, a1=0.f, a2=0.f, a3=0.f;
        const float* r0 = &hc[(rr*4+0)*1200];
        const float* r1 = &hc[(rr*4+1)*1200];
        const float* r2 = &hc[(rr*4+2)*1200];
        const float* r3 = &hc[(rr*4+3)*1200];
        for (int k = 0; k < 1200; ++k) {
            float wm = Wm[(size_t)k*121 + j];
            a0 += r0[k]*wm; a1 += r1[k]*wm; a2 += r2[k]*wm; a3 += r3[k]*wm;
        }
        float bb = bm[j];
        yy[(rr*4+0)*121 + j] = a0 + bb;
        yy[(rr*4+1)*121 + j] = a1 + bb;
        yy[(rr*4+2)*121 + j] = a2 + bb;
        yy[(rr*4+3)*121 + j] = a3 + bb;
    }
    __syncthreads();
    if (tid < 8) {
        const float* yr = &yy[tid*121];
        float m = yr[1];
        for (int q = 2; q < 21; ++q) m = fmaxf(m, yr[q]);
        float ssum = 0.f;
        for (int q = 1; q < 21; ++q) ssum += expf(yr[q] - m);
        sm2[tid*2] = m; sm2[tid*2+1] = ssum;
    }
    __syncthreads();
    if (j < 121) {
        for (int i2 = 0; i2 < 4; ++i2) {
            int i = rr*4 + i2;
            long r = rowbase + i; int t = (int)(r >> 5), b = (int)(r & 31);
            float y = yy[i*121 + j], o;
            if (j == 0)      o = 1.f/(1.f + expf(-y));
            else if (j < 21) o = expf(y - sm2[i*2]) / sm2[i*2+1];
            else if (j < 61) o = y;
            else if (j < 101) o = expf(y);
            else             o = tanhf(y);
            out[((size_t)b*600 + t)*121 + j] = o;
        }
    }
}

extern "C" void kernel_launch(void* const* d_in, const int* in_sizes, int n_in,
                              void* d_out, int out_size, void* d_ws, size_t ws_size,
                              hipStream_t stream) {
    const float* strokes  = (const float*)d_in[0];
    const float* sentence = (const float*)d_in[1];
    const float* W1  = (const float*)d_in[2];
    const float* U1r = (const float*)d_in[3];
    const float* b1  = (const float*)d_in[4];
    const float* Ww  = (const float*)d_in[5];
    const float* bw  = (const float*)d_in[6];
    const float* W2  = (const float*)d_in[7];
    const float* U2r = (const float*)d_in[8];
    const float* b2  = (const float*)d_in[9];
    const float* W3  = (const float*)d_in[10];
    const float* U3r = (const float*)d_in[11];
    const float* b3  = (const float*)d_in[12];
    const float* Wm  = (const float*)d_in[13];
    const float* bm  = (const float*)d_in[14];
    float* ws = (float*)d_ws;
    float* out = (float*)d_out;

    const int dyn_bytes = LDS_TOT * 4;   // 142400
    (void)hipFuncSetAttribute((const void*)hw_main,
                              hipFuncAttributeMaxDynamicSharedMemorySize, dyn_bytes);

    init_ws<<<dim3(4), dim3(512), 0, stream>>>((unsigned*)ws);
    build_ut<<<dim3(1024), dim3(256), 0, stream>>>(ws, W1, U1r, W2, U2r, W3, U3r, Ww, sentence);
    hw_main<<<dim3(NBLK), dim3(512), dyn_bytes, stream>>>(ws, strokes, sentence, b1, b2, b3, bw);
    out_proj<<<dim3(2400), dim3(256), 0, stream>>>(ws, Wm, bm, out);
}

// Round 12
// 10345.469 us; speedup vs baseline: 2.6919x; 2.6919x over previous
//
#include <hip/hip_runtime.h>
#include <math.h>

#define T 600
#define NBLK 235

// ---------- sync layout (uints in ws[0..8192)) ----------
#define FL1 256
#define FL2 768
#define FL3 1280
#define FLB 1792
#define SH1 2304
#define SH2 2880
#define SH3 3520

// ---------- ws float offsets ----------
#define OFF_UT1 8192
#define SZ_UT1 (1600*480)
#define OFF_UT2 (OFF_UT1 + SZ_UT1)
#define SZ_UT2 (1600*960)
#define OFF_UT3 (OFF_UT2 + SZ_UT2)
#define OFF_WWT (OFF_UT3 + SZ_UT2)
#define SZ_WWT (30*400)
#define OFF_H1 (OFF_WWT + SZ_WWT)
#define SZ_H (600*32*400)
#define OFF_H2 (OFF_H1 + SZ_H)
#define OFF_H3 (OFF_H2 + SZ_H)
#define OFF_W  (OFF_H3 + SZ_H)
#define SZ_W (600*32*61)

// ---------- dynamic LDS float offsets (roles 0..2) ----------
#define LDS_W    0
#define LDS_V    19280
#define LDS_Z    34640
#define LDS_C    35408
#define LDS_TOT  35600        // 142400 bytes

__device__ __forceinline__ float sigm(float x) { return 1.f/(1.f+expf(-x)); }

// wave-internal phase fence: drain LDS ops, pin scheduling
#define WBAR() do { \
    asm volatile("s_waitcnt lgkmcnt(0)" ::: "memory"); \
    __builtin_amdgcn_sched_barrier(0); \
} while (0)

__global__ void init_ws(unsigned* uws) {
    for (int i = threadIdx.x + blockIdx.x*blockDim.x; i < 8192; i += blockDim.x*gridDim.x)
        uws[i] = 0u;
}

__global__ void build_ut(float* __restrict__ ws,
                         const float* __restrict__ W1, const float* __restrict__ U1r,
                         const float* __restrict__ W2, const float* __restrict__ U2r,
                         const float* __restrict__ W3, const float* __restrict__ U3r,
                         const float* __restrict__ Ww) {
    const long N1 = 1600L*480, N2 = 1600L*960;
    const long total = N1 + 2*N2 + 30L*400;
    for (long i = blockIdx.x*(long)blockDim.x + threadIdx.x; i < total;
         i += (long)gridDim.x*blockDim.x) {
        if (i < N1) {
            long c = i / 480, k = i % 480;
            float v = 0.f;
            if (k < 64) v = W1[k*1600 + c];
            else if (k < 464) v = U1r[(k-64)*1600 + c];
            ws[OFF_UT1 + c*480 + k] = v;
        } else if (i < N1 + N2) {
            long ii = i - N1; long c = ii/960, k = ii%960;
            float v = 0.f;
            if (k < 464) v = W2[k*1600 + c];
            else if (k >= 480 && k < 880) v = U2r[(k-480)*1600 + c];
            ws[OFF_UT2 + c*960 + k] = v;
        } else if (i < N1 + 2*N2) {
            long ii = i - N1 - N2; long c = ii/960, k = ii%960;
            float v = 0.f;
            if (k < 464) v = W3[k*1600 + c];
            else if (k >= 480 && k < 880) v = U3r[(k-480)*1600 + c];
            ws[OFF_UT3 + c*960 + k] = v;
        } else {
            long ii = i - N1 - 2*N2; long n = ii/400, k = ii%400;
            ws[OFF_WWT + n*400 + k] = Ww[k*30 + n];
        }
    }
}

// ---------- sync primitives (clean-line protocol, R10-verified) ----------
__device__ __forceinline__ unsigned ld_cohere(const unsigned* p) {
    unsigned v;
    asm volatile("global_load_dword %0, %1, off sc0 sc1\n\t"
                 "s_waitcnt vmcnt(0)"
                 : "=v"(v) : "v"(p) : "memory");
    return v;
}
__device__ __forceinline__ void st_wt(float* p, float v) {
    asm volatile("global_store_dword %0, %1, off sc0 sc1\n\t"
                 "s_waitcnt vmcnt(0)"
                 :: "v"(p), "v"(v) : "memory");
}
__device__ __forceinline__ void publish(unsigned* flags, unsigned v) {
    #pragma unroll
    for (int r = 0; r < 8; ++r)
        asm volatile("global_store_dword %0, %1, off sc0 sc1"
                     :: "v"(flags + r*64), "v"(v) : "memory");
    asm volatile("s_waitcnt vmcnt(0)" ::: "memory");
}
__device__ __forceinline__ void wait_flag(const unsigned* p, unsigned tgt) {
    int it = 0;
    while (ld_cohere(p) < tgt) {
        if (it > 64) __builtin_amdgcn_s_sleep(2);
        ++it;
    }
}
__device__ __forceinline__ void arrive2(unsigned* shard, unsigned gsize,
                                        unsigned* master, unsigned n,
                                        unsigned* flags, unsigned ep1) {
    unsigned old = __hip_atomic_fetch_add(shard, 1u, __ATOMIC_RELAXED,
                                          __HIP_MEMORY_SCOPE_AGENT);
    if (old + 1u == gsize * ep1) {
        unsigned o2 = __hip_atomic_fetch_add(master, gsize, __ATOMIC_RELAXED,
                                             __HIP_MEMORY_SCOPE_AGENT);
        if (o2 + gsize == n * ep1) publish(flags, ep1);
    }
}
__device__ __forceinline__ void arrive1(unsigned* master, unsigned n,
                                        unsigned* flags, unsigned ep1) {
    unsigned old = __hip_atomic_fetch_add(master, 1u, __ATOMIC_RELAXED,
                                          __HIP_MEMORY_SCOPE_AGENT);
    if (old + 1u == n * ep1) publish(flags, ep1);
}

// ---------- GEMM inner pass over kf range [LO,HI) ----------
template<int NQ, int KCN, int K4S, int LO, int HI>
__device__ __forceinline__ void gemm_pass(const float4* __restrict__ w4,
                                          const float4* __restrict__ v4,
                                          int lc0, int kc, int bq, int kofs4,
                                          float acc[8][4]) {
    #pragma unroll
    for (int q = 0; q < NQ; ++q) {
        int kfv = q*KCN + kc;
        if (kfv >= LO && kfv < HI) {
            int xv = kfv ^ ((kfv >> 3) & 7);
            int kfw = kofs4 + kfv;
            int xw = kfw ^ ((kfw >> 3) & 7);
            float4 va[8];
            #pragma unroll
            for (int i = 0; i < 8; ++i) va[i] = v4[(bq*8+i)*120 + xv];
            #pragma unroll
            for (int j = 0; j < 4; ++j) {
                float4 u = w4[(lc0+j)*K4S + xw];
                #pragma unroll
                for (int i = 0; i < 8; ++i)
                    acc[i][j] += va[i].x*u.x + va[i].y*u.y + va[i].z*u.z + va[i].w*u.w;
            }
        }
    }
}

__launch_bounds__(512)
__global__ void hw_main(float* __restrict__ ws,
                        const float* __restrict__ strokes, const float* __restrict__ sentence,
                        const float* __restrict__ b1, const float* __restrict__ b2,
                        const float* __restrict__ b3, const float* __restrict__ bw) {
    extern __shared__ float S[];
    const int tid = threadIdx.x;
    const int bid = blockIdx.x;
    unsigned* uws = (unsigned*)ws;
    unsigned* root1 = uws + 0;
    unsigned* root2 = uws + 64;
    unsigned* root3 = uws + 128;
    unsigned* rootB = uws + 192;
    const int rep = (bid & 7) * 64;
    const unsigned* fl1r = uws + FL1 + rep;
    const unsigned* fl2r = uws + FL2 + rep;
    const unsigned* flBr = uws + FLB + rep;

    // roles: [0,67) L1 ; [67,147) L2 ; [147,227) L3 ; [227,235) ATT
    int role, unit0 = 0, nu = 0, L = 0, b0a = 0;
    const float* utp = nullptr; const float* biasp = nullptr; float* hout = nullptr;
    if (bid < 67)       { role = 0; L = bid;      unit0 = L*6; nu = (bid==66)?4:6; utp = ws+OFF_UT1; biasp = b1; hout = ws+OFF_H1; }
    else if (bid < 147) { role = 1; L = bid-67;   unit0 = L*5; nu = 5;             utp = ws+OFF_UT2; biasp = b2; hout = ws+OFF_H2; }
    else if (bid < 227) { role = 2; L = bid-147;  unit0 = L*5; nu = 5;             utp = ws+OFF_UT3; biasp = b3; hout = ws+OFF_H3; }
    else                { role = 3; b0a = (bid-227)*4; }

    if (role <= 2) {
        const int NC = 4*nu;
        const int KCN = (role == 0) ? 20 : 24;
        const int K4S = (role == 0) ? 121 : 241;
        const int K4TOT = (role == 0) ? 120 : 240;
        const int uts = (role == 0) ? 480 : 960;
        float4* w4 = (float4*)S;
        float4* v4 = (float4*)(S + LDS_V);
        float*  vf = S + LDS_V;
        float*  z_lds = S + LDS_Z;
        float*  c_lds = S + LDS_C;

        for (int idx = tid; idx < NC*K4TOT; idx += 512) {
            int colL = idx / K4TOT, kf = idx % K4TOT;
            int gcol = (colL/nu)*400 + unit0 + (colL%nu);
            float4 val = *(const float4*)(utp + (size_t)gcol*uts + kf*4);
            w4[colL*K4S + (kf ^ ((kf>>3)&7))] = val;
        }
        for (int i = tid; i < 192; i += 512) c_lds[i] = 0.f;

        const int tile = tid / KCN, kc = tid % KCN;
        const int bq = tile / nu, cq = tile % nu;
        const bool act = (tile < 4*nu);
        float bias0 = 0.f, bias1 = 0.f;
        if (tid < 32*NC)       { int lc = tid % NC;        bias0 = biasp[(lc/nu)*400 + unit0 + (lc%nu)]; }
        if (tid + 512 < 32*NC) { int lc = (tid+512) % NC;  bias1 = biasp[(lc/nu)*400 + unit0 + (lc%nu)]; }
        const unsigned nrole = (role == 0) ? 67u : 80u;
        unsigned* mymaster = (role == 0) ? root1 : ((role == 1) ? root2 : root3);
        unsigned* myfl     = uws + ((role == 0) ? FL1 : ((role == 1) ? FL2 : FL3));
        const unsigned* myflr = uws + ((role == 0) ? FL1 : ((role == 1) ? FL2 : FL3)) + rep;
        unsigned* myshard;
        {
            int shbase = (role == 0) ? SH1 : ((role == 1) ? SH2 : SH3);
            myshard = uws + shbase + (L >> 3) * 64;
        }
        const unsigned gsize = (unsigned)(((int)nrole - (L >> 3)*8 < 8) ? ((int)nrole - (L >> 3)*8) : 8);
        __syncthreads();

        for (int t = 0; t < T; ++t) {
            float acc[8][4];
            #pragma unroll
            for (int i = 0; i < 8; ++i)
                #pragma unroll
                for (int j = 0; j < 4; ++j) acc[i][j] = 0.f;

            if (role == 0) {
                // ---- L1(t): h-part early (overlaps ATT(t-1)); w-part after flB(t) ----
                if (tid == 0 && t > 0) wait_flag(myflr, (unsigned)t);
                __syncthreads();
                const float* hsrc = (t > 0) ? (ws + OFF_H1 + (size_t)(t-1)*12800) : nullptr;
                for (int idx = tid; idx < 32*104; idx += 512) {
                    int b = idx/104, kf = 16 + idx%104;
                    float4 val = {0.f,0.f,0.f,0.f};
                    if (kf < 116 && hsrc) val = *(const float4*)(hsrc + b*400 + (kf*4 - 64));
                    v4[b*120 + (kf ^ ((kf>>3)&7))] = val;
                }
                __syncthreads();
                if (act) gemm_pass<6,20,121,16,116>(w4, v4, cq*4, kc, bq, 0, acc);
                if (tid == 0 && t > 0) wait_flag(flBr, (unsigned)t);
                __syncthreads();
                const float* wsrc = (t > 0) ? (ws + OFF_W + (size_t)(t-1)*1952) : nullptr;
                {
                    int b = tid / 16, kf = tid % 16;
                    if (b < 32) {
                        float4 val;
                        if (kf == 0) {
                            const float* xp = strokes + ((size_t)b*600 + t)*3;
                            val.x = xp[0]; val.y = xp[1]; val.z = xp[2];
                            val.w = wsrc ? wsrc[b*61] : 0.f;
                        } else {
                            int k0 = kf*4 - 3;
                            if (wsrc) { val.x = wsrc[b*61+k0]; val.y = wsrc[b*61+k0+1];
                                        val.z = wsrc[b*61+k0+2]; val.w = wsrc[b*61+k0+3]; }
                            else { val.x=val.y=val.z=val.w=0.f; }
                        }
                        v4[b*120 + (kf ^ ((kf>>3)&7))] = val;
                    }
                }
                __syncthreads();
                if (act) gemm_pass<6,20,121,0,16>(w4, v4, cq*4, kc, bq, 0, acc);
            } else {
                // ---- L2/L3(t): h-part after up-flag; w-part after flB; pass2 after own flag ----
                if (tid == 0) wait_flag((role==1) ? fl1r : fl2r, (unsigned)(t+1));
                __syncthreads();
                const float* hsrc = ws + ((role==1)?OFF_H1:OFF_H2) + (size_t)t*12800;
                for (int idx = tid; idx < 32*104; idx += 512) {
                    int b = idx/104, kf = 16 + idx%104;
                    float4 val = {0.f,0.f,0.f,0.f};
                    if (kf < 116) val = *(const float4*)(hsrc + b*400 + (kf*4 - 64));
                    v4[b*120 + (kf ^ ((kf>>3)&7))] = val;
                }
                __syncthreads();
                if (act) gemm_pass<5,24,241,16,116>(w4, v4, cq*4, kc, bq, 0, acc);
                if (tid == 0) wait_flag(flBr, (unsigned)(t+1));
                __syncthreads();
                const float* wsrc = ws + OFF_W + (size_t)t*1952;
                {
                    int b = tid / 16, kf = tid % 16;
                    if (b < 32) {
                        float4 val;
                        if (kf == 0) {
                            const float* xp = strokes + ((size_t)b*600 + t)*3;
                            val.x = xp[0]; val.y = xp[1]; val.z = xp[2];
                            val.w = wsrc[b*61];
                        } else {
                            int k0 = kf*4 - 3;
                            val.x = wsrc[b*61+k0]; val.y = wsrc[b*61+k0+1];
                            val.z = wsrc[b*61+k0+2]; val.w = wsrc[b*61+k0+3];
                        }
                        v4[b*120 + (kf ^ ((kf>>3)&7))] = val;
                    }
                }
                __syncthreads();
                if (act) gemm_pass<5,24,241,0,16>(w4, v4, cq*4, kc, bq, 0, acc);
                __syncthreads();
                if (tid == 0 && t > 0) wait_flag(myflr, (unsigned)t);
                __syncthreads();
                const float* hp2 = (t > 0) ? (ws + ((role==1)?OFF_H2:OFF_H3) + (size_t)(t-1)*12800) : nullptr;
                for (int idx = tid; idx < 32*120; idx += 512) {
                    int b = idx/120, kf = idx%120;
                    float4 val = {0.f,0.f,0.f,0.f};
                    if (kf < 100 && hp2) val = *(const float4*)(hp2 + b*400 + kf*4);
                    v4[b*120 + (kf ^ ((kf>>3)&7))] = val;
                }
                __syncthreads();
                if (act) gemm_pass<5,24,241,0,100>(w4, v4, cq*4, kc, bq, 120, acc);
            }

            // ---- split-K reduction (scratch aliases v) ----
            __syncthreads();
            const int halfk = (KCN+1)/2;
            const int SCRW = NC*32 + 4;
            const int NO = 32*NC;
            if (act && kc < halfk) {
                #pragma unroll
                for (int i = 0; i < 8; ++i) {
                    float4 w;
                    w.x=acc[i][0]; w.y=acc[i][1]; w.z=acc[i][2]; w.w=acc[i][3];
                    *(float4*)&vf[kc*SCRW + (bq*8+i)*NC + cq*4] = w;
                }
            }
            __syncthreads();
            float zs0 = 0.f, zs1 = 0.f;
            if (tid < NO)       for (int k2 = 0; k2 < halfk; ++k2) zs0 += vf[k2*SCRW + tid];
            if (tid + 512 < NO) for (int k2 = 0; k2 < halfk; ++k2) zs1 += vf[k2*SCRW + tid + 512];
            __syncthreads();
            if (act && kc >= halfk) {
                #pragma unroll
                for (int i = 0; i < 8; ++i) {
                    float4 w;
                    w.x=acc[i][0]; w.y=acc[i][1]; w.z=acc[i][2]; w.w=acc[i][3];
                    *(float4*)&vf[(kc-halfk)*SCRW + (bq*8+i)*NC + cq*4] = w;
                }
            }
            __syncthreads();
            const int rem = KCN - halfk;
            if (tid < NO) {
                for (int k2 = 0; k2 < rem; ++k2) zs0 += vf[k2*SCRW + tid];
                z_lds[tid] = zs0 + bias0;
            }
            if (tid + 512 < NO) {
                for (int k2 = 0; k2 < rem; ++k2) zs1 += vf[k2*SCRW + tid + 512];
                z_lds[tid + 512] = zs1 + bias1;
            }
            __syncthreads();
            if (tid < 32*nu) {
                int b = tid & 31, ju = tid >> 5;
                float zi = z_lds[b*NC + ju];
                float zf = z_lds[b*NC + nu + ju];
                float zg = z_lds[b*NC + 2*nu + ju];
                float zo = z_lds[b*NC + 3*nu + ju];
                float cP = c_lds[b*6 + ju];
                float cN = sigm(zf)*cP + sigm(zi)*tanhf(zg);
                float hN = sigm(zo)*tanhf(cN);
                c_lds[b*6 + ju] = cN;
                st_wt(&hout[(size_t)t*12800 + b*400 + unit0 + ju], hN);
            }
            __syncthreads();
            if (tid == 0) arrive2(myshard, gsize, mymaster, nrole, myfl, (unsigned)(t+1));
        }
    } else {
        // ------------- ATT block: PER-WAVE, barrier-free chain -------------
        // wave wv (0..3) owns batch b0a+wv; waves 4..7 idle.
        const int wv = tid >> 6, lane = tid & 63;
        float* hb   = S;                    // 4 x 400
        float* pb   = S + 1600 + (tid>>6)*32;   // per-wave 30 (stride 32)
        float* ab   = S + 1792 + (tid>>6)*32;   // alpha[0..9], beta[16..25]
        float* kap  = S + 1984 + (tid>>6)*16;   // per-wave 10
        float* phiW = S + 2112 + (tid>>6)*64;   // per-wave 64
        float* sentl= S + 2368;             // 15616
        float* wwt  = S + 2368 + 15616;     // 30 x 404 = 12120 (ends 30104)
        float* hbW  = hb + wv*400;
        float4* hb4 = (float4*)hbW;

        for (int i = tid; i < 64; i += 512) (S + 1984)[i] = 0.f;   // kappa init (all waves)
        for (int i = tid; i < 15616; i += 512) sentl[i] = sentence[(size_t)b0a*3904 + i];
        for (int i = tid; i < 12000; i += 512) {
            int n = i/400, k = i%400;
            wwt[n*404 + k] = ws[OFF_WWT + i];
        }
        float bwv = (lane < 60 && !(lane & 1)) ? bw[lane >> 1] : 0.f;
        __syncthreads();

        for (int t = 0; t < T; ++t) {
            if (wv < 4) {
                // all lanes poll (same address -> coalesced broadcast)
                {
                    int it = 0;
                    while (ld_cohere(fl1r) < (unsigned)(t+1)) {
                        if (it > 64) __builtin_amdgcn_s_sleep(2);
                        ++it;
                    }
                }
                // stage h1(t) for this batch (100 float4)
                const float* h1t = ws + OFF_H1 + (size_t)t*12800 + (size_t)(b0a+wv)*400;
                for (int i = lane; i < 100; i += 64)
                    hb4[i] = *(const float4*)(h1t + i*4);
                WBAR();
                // p[n] = h . WwT[n] + bw[n]   (2 lanes per n, shfl combine)
                if (lane < 60) {
                    int n = lane >> 1, hf = lane & 1;
                    const float4* ww4 = (const float4*)(wwt + n*404) + hf*50;
                    const float4* hh4 = hb4 + hf*50;
                    float a = 0.f;
                    #pragma unroll 5
                    for (int i = 0; i < 50; ++i) {
                        float4 h = hh4[i], w = ww4[i];
                        a += h.x*w.x + h.y*w.y + h.z*w.z + h.w*w.w;
                    }
                    a += __shfl_xor(a, 1);
                    if (hf == 0) pb[n] = a + bwv;
                }
                WBAR();
                if (lane < 10) {
                    ab[lane]      = expf(pb[lane]);
                    ab[16 + lane] = expf(pb[10 + lane]);
                    kap[lane]    += expf(pb[20 + lane]);
                }
                WBAR();
                {
                    float uf = (float)lane, ph = 0.f;
                    #pragma unroll
                    for (int k0 = 0; k0 < 10; ++k0) {
                        float d = kap[k0] - uf;
                        ph += ab[k0]*expf(-ab[16 + k0]*d*d);
                    }
                    phiW[lane] = ph;
                }
                WBAR();
                if (lane < 61) {
                    const float* sp = sentl + wv*3904 + lane;
                    float wvv = 0.f;
                    #pragma unroll 4
                    for (int u = 0; u < 64; ++u) wvv += phiW[u]*sp[u*61];
                    st_wt(&ws[OFF_W + (size_t)t*1952 + (size_t)(b0a+wv)*61 + lane], wvv);
                }
            }
            __syncthreads();
            if (tid == 0) arrive1(rootB, 8u, uws + FLB, (unsigned)(t+1));
        }
    }
}

__launch_bounds__(256)
__global__ void out_proj(const float* __restrict__ ws, const float* __restrict__ Wm,
                         const float* __restrict__ bm, float* __restrict__ out) {
    __shared__ __align__(16) float hc[8*1200];
    __shared__ float yy[8*121];
    __shared__ float sm2[16];
    const int tid = threadIdx.x;
    const long rowbase = (long)blockIdx.x * 8;
    const float* h1h = ws + OFF_H1;
    const float* h2h = ws + OFF_H2;
    const float* h3h = ws + OFF_H3;
    for (int idx = tid; idx < 8*1200; idx += 256) {
        int i = idx/1200, k = idx%1200;
        long r = rowbase + i; int t = (int)(r >> 5), b = (int)(r & 31);
        float v;
        if (k < 400)      v = h1h[(size_t)t*12800 + b*400 + k];
        else if (k < 800) v = h2h[(size_t)t*12800 + b*400 + (k-400)];
        else              v = h3h[(size_t)t*12800 + b*400 + (k-800)];
        hc[i*1200 + k] = v;
    }
    __syncthreads();
    const int j = tid & 127, rr = tid >> 7;
    if (j < 121) {
        float a0=0.f, a1=0.f, a2=0.f, a3=0.f;
        const float* r0 = &hc[(rr*4+0)*1200];
        const float* r1 = &hc[(rr*4+1)*1200];
        const float* r2 = &hc[(rr*4+2)*1200];
        const float* r3 = &hc[(rr*4+3)*1200];
        for (int k = 0; k < 1200; ++k) {
            float wm = Wm[(size_t)k*121 + j];
            a0 += r0[k]*wm; a1 += r1[k]*wm; a2 += r2[k]*wm; a3 += r3[k]*wm;
        }
        float bb = bm[j];
        yy[(rr*4+0)*121 + j] = a0 + bb;
        yy[(rr*4+1)*121 + j] = a1 + bb;
        yy[(rr*4+2)*121 + j] = a2 + bb;
        yy[(rr*4+3)*121 + j] = a3 + bb;
    }
    __syncthreads();
    if (tid < 8) {
        const float* yr = &yy[tid*121];
        float m = yr[1];
        for (int q = 2; q < 21; ++q) m = fmaxf(m, yr[q]);
        float ssum = 0.f;
        for (int q = 1; q < 21; ++q) ssum += expf(yr[q] - m);
        sm2[tid*2] = m; sm2[tid*2+1] = ssum;
    }
    __syncthreads();
    if (j < 121) {
        for (int i2 = 0; i2 < 4; ++i2) {
            int i = rr*4 + i2;
            long r = rowbase + i; int t = (int)(r >> 5), b = (int)(r & 31);
            float y = yy[i*121 + j], o;
            if (j == 0)      o = 1.f/(1.f + expf(-y));
            else if (j < 21) o = expf(y - sm2[i*2]) / sm2[i*2+1];
            else if (j < 61) o = y;
            else if (j < 101) o = expf(y);
            else             o = tanhf(y);
            out[((size_t)b*600 + t)*121 + j] = o;
        }
    }
}

extern "C" void kernel_launch(void* const* d_in, const int* in_sizes, int n_in,
                              void* d_out, int out_size, void* d_ws, size_t ws_size,
                              hipStream_t stream) {
    const float* strokes  = (const float*)d_in[0];
    const float* sentence = (const float*)d_in[1];
    const float* W1  = (const float*)d_in[2];
    const float* U1r = (const float*)d_in[3];
    const float* b1  = (const float*)d_in[4];
    const float* Ww  = (const float*)d_in[5];
    const float* bw  = (const float*)d_in[6];
    const float* W2  = (const float*)d_in[7];
    const float* U2r = (const float*)d_in[8];
    const float* b2  = (const float*)d_in[9];
    const float* W3  = (const float*)d_in[10];
    const float* U3r = (const float*)d_in[11];
    const float* b3  = (const float*)d_in[12];
    const float* Wm  = (const float*)d_in[13];
    const float* bm  = (const float*)d_in[14];
    float* ws = (float*)d_ws;
    float* out = (float*)d_out;

    const int dyn_bytes = LDS_TOT * 4;   // 142400
    (void)hipFuncSetAttribute((const void*)hw_main,
                              hipFuncAttributeMaxDynamicSharedMemorySize, dyn_bytes);

    init_ws<<<dim3(4), dim3(512), 0, stream>>>((unsigned*)ws);
    build_ut<<<dim3(1024), dim3(256), 0, stream>>>(ws, W1, U1r, W2, U2r, W3, U3r, Ww);
    hw_main<<<dim3(NBLK), dim3(512), dyn_bytes, stream>>>(ws, strokes, sentence, b1, b2, b3, bw);
    out_proj<<<dim3(2400), dim3(256), 0, stream>>>(ws, Wm, bm, out);
}